// Round 1
// baseline (268.014 us; speedup 1.0000x reference)
//
#include <hip/hip_runtime.h>

// Problem: MaskPatchClassificationHead — B=4, P=256, F_IN=F_OUT=512
// loss = KL(dist || softmax(x x^T / tau)) batchmean, x = normalize(inputs@W^T + b)
// dist[b,p,q] = eq(labels[b,p], labels[b,q]) / n_p  (exact row equality == d_L1==0)

#define TAU 0.07f
#define EPSC 1e-5f
constexpr int Bz = 4;
constexpr int Pn = 256;
constexpr int F  = 512;

__device__ __forceinline__ float wave_reduce_sum(float v) {
  #pragma unroll
  for (int off = 32; off > 0; off >>= 1) v += __shfl_down(v, off, 64);
  return v;
}
__device__ __forceinline__ float wave_reduce_max(float v) {
  #pragma unroll
  for (int off = 32; off > 0; off >>= 1) v = fmaxf(v, __shfl_down(v, off, 64));
  return v;
}

// One block per output row n in [0, B*P). 256 threads; thread t computes
// outputs o=t and o=t+256 (dot-512 each), then block-normalizes the row.
__global__ __launch_bounds__(256) void fc_norm_kernel(
    const float* __restrict__ in, const float* __restrict__ W,
    const float* __restrict__ bias, float* __restrict__ x) {
  const int n = blockIdx.x;
  const int t = threadIdx.x;
  __shared__ float arow[F];
  __shared__ float sm[4];

  ((float2*)arow)[t] = ((const float2*)(in + (size_t)n * F))[t];
  __syncthreads();

  float acc0 = bias[t];
  float acc1 = bias[t + 256];
  const float4* w0 = (const float4*)(W + (size_t)t * F);
  const float4* w1 = (const float4*)(W + (size_t)(t + 256) * F);
  const float4* a4 = (const float4*)arow;
  #pragma unroll 8
  for (int i = 0; i < F / 4; ++i) {
    float4 a = a4[i];
    float4 wa = w0[i];
    float4 wb = w1[i];
    acc0 = fmaf(a.x, wa.x, fmaf(a.y, wa.y, fmaf(a.z, wa.z, fmaf(a.w, wa.w, acc0))));
    acc1 = fmaf(a.x, wb.x, fmaf(a.y, wb.y, fmaf(a.z, wb.z, fmaf(a.w, wb.w, acc1))));
  }

  float ss = acc0 * acc0 + acc1 * acc1;
  ss = wave_reduce_sum(ss);
  if ((t & 63) == 0) sm[t >> 6] = ss;
  __syncthreads();
  float nrm = sqrtf(sm[0] + sm[1] + sm[2] + sm[3]);
  float inv = 1.0f / fmaxf(nrm, 1e-12f);
  x[(size_t)n * F + t]       = acc0 * inv;
  x[(size_t)n * F + t + 256] = acc1 * inv;
}

// One block per (b,p). Thread t handles q=t: dot(x_p, x_q), exact equality of
// label rows, then row softmax + clip + KL contribution; one atomicAdd/block.
__global__ __launch_bounds__(256) void loss_kernel(
    const float* __restrict__ x, const float* __restrict__ labels,
    float* __restrict__ acc) {
  const int bp = blockIdx.x;        // b*256 + p
  const int bb = bp >> 8;
  const int t = threadIdx.x;        // q
  __shared__ float xp[F];
  __shared__ float lp[F];
  __shared__ float sm[4];

  ((float2*)xp)[t] = ((const float2*)(x + (size_t)bp * F))[t];
  ((float2*)lp)[t] = ((const float2*)(labels + (size_t)bp * F))[t];
  __syncthreads();

  const float4* xq = (const float4*)(x + (size_t)(bb * 256 + t) * F);
  const float4* lq = (const float4*)(labels + (size_t)(bb * 256 + t) * F);
  const float4* xp4 = (const float4*)xp;
  const float4* lp4 = (const float4*)lp;

  float dot = 0.f;
  bool eq = true;
  #pragma unroll 4
  for (int i = 0; i < F / 4; ++i) {
    float4 a = xp4[i];
    float4 v = xq[i];
    dot = fmaf(a.x, v.x, fmaf(a.y, v.y, fmaf(a.z, v.z, fmaf(a.w, v.w, dot))));
    float4 c = lp4[i];
    float4 d = lq[i];
    eq = eq && (c.x == d.x) && (c.y == d.y) && (c.z == d.z) && (c.w == d.w);
  }

  float s = dot * (1.0f / TAU);

  // row max
  float m = wave_reduce_max(s);
  if ((t & 63) == 0) sm[t >> 6] = m;
  __syncthreads();
  m = fmaxf(fmaxf(sm[0], sm[1]), fmaxf(sm[2], sm[3]));
  float e = __expf(0.0f) * expf(s - m);  // plain expf; keep precise path
  __syncthreads();

  // row sum
  float z = wave_reduce_sum(e);
  if ((t & 63) == 0) sm[t >> 6] = z;
  __syncthreads();
  z = sm[0] + sm[1] + sm[2] + sm[3];

  float prob = e / z;
  prob = fminf(fmaxf(prob, EPSC), 1.0f - EPSC);
  float logp = logf(prob);
  __syncthreads();

  // count of equal rows (n_p)
  float cnt = wave_reduce_sum(eq ? 1.0f : 0.0f);
  if ((t & 63) == 0) sm[t >> 6] = cnt;
  __syncthreads();
  float n = sm[0] + sm[1] + sm[2] + sm[3];

  // pointwise = dist * (log dist - log prob) = (1/n) * (-log n - log prob)
  float contrib = eq ? (-logf(n) - logp) / n : 0.0f;
  __syncthreads();
  contrib = wave_reduce_sum(contrib);
  if ((t & 63) == 0) sm[t >> 6] = contrib;
  __syncthreads();
  if (t == 0) atomicAdd(acc, sm[0] + sm[1] + sm[2] + sm[3]);
}

__global__ void finalize_kernel(const float* __restrict__ acc,
                                float* __restrict__ out) {
  out[0] = acc[0] * (1.0f / (float)(Bz * Pn));
}

extern "C" void kernel_launch(void* const* d_in, const int* in_sizes, int n_in,
                              void* d_out, int out_size, void* d_ws, size_t ws_size,
                              hipStream_t stream) {
  const float* inputs = (const float*)d_in[0];
  const float* labels = (const float*)d_in[1];
  const float* W      = (const float*)d_in[2];
  const float* bias   = (const float*)d_in[3];
  float* out = (float*)d_out;

  float* acc = (float*)d_ws;                       // 1 float accumulator
  float* x   = (float*)((char*)d_ws + 256);        // B*P*F floats = 2 MB

  hipMemsetAsync(acc, 0, sizeof(float), stream);
  fc_norm_kernel<<<Bz * Pn, 256, 0, stream>>>(inputs, W, bias, x);
  loss_kernel<<<Bz * Pn, 256, 0, stream>>>(x, labels, acc);
  finalize_kernel<<<1, 1, 0, stream>>>(acc, out);
}

// Round 2
// 120.428 us; speedup vs baseline: 2.2255x; 2.2255x over previous
//
#include <hip/hip_runtime.h>

// MaskPatchClassificationHead — B=4, P=256, F=512
// loss = KL(dist || softmax(x x^T / tau)) batchmean, x = normalize(inputs@W^T + b)
// Pipeline: fc GEMM (K-split partials) -> label sigs -> scores GEMM (h h^T, norms
// from diagonal) -> per-row softmax/KL -> finalize.

#define INV_TAU (1.0f / 0.07f)
#define EPSC 1e-5f

constexpr int Bz = 4;
constexpr int Pn = 256;
constexpr int Fdim = 512;
constexpr int Mrows = Bz * Pn;                    // 1024
constexpr size_t HP_STRIDE = (size_t)Mrows * Fdim;  // per K-half h partial
constexpr size_t SP_STRIDE = (size_t)Bz * Pn * Pn;  // per K-half score partial

__device__ __forceinline__ float wave_sum(float v) {
  #pragma unroll
  for (int o = 32; o > 0; o >>= 1) v += __shfl_down(v, o, 64);
  return v;
}
__device__ __forceinline__ float wave_max(float v) {
  #pragma unroll
  for (int o = 32; o > 0; o >>= 1) v = fmaxf(v, __shfl_down(v, o, 64));
  return v;
}

// ---------------- fc partial GEMM: hp[z][m][n] = sum_{k in half z} A[m][k] W[n][k]
// 64x64 tile, 4x4 micro, BK=32. grid (16, 8, 2), 256 threads.
__global__ __launch_bounds__(256) void fc_gemm(const float* __restrict__ A,
                                               const float* __restrict__ W,
                                               float* __restrict__ hp) {
  const int m0 = blockIdx.x * 64, n0 = blockIdx.y * 64;
  const int kbase = blockIdx.z * 256;
  float* C = hp + (size_t)blockIdx.z * HP_STRIDE;
  __shared__ float Ash[32][68];  // [k][m], transposed
  __shared__ float Bsh[32][68];  // [k][n]
  const int t = threadIdx.x, tx = t & 15, ty = t >> 4;
  const int r0 = t >> 3, c0 = (t & 7) << 2;  // second float4: row r0+32, same c0
  float acc[4][4] = {};

  for (int kc = 0; kc < 256; kc += 32) {
    const float* Ap = A + (size_t)(m0 + r0) * Fdim + kbase + kc + c0;
    const float* Wp = W + (size_t)(n0 + r0) * Fdim + kbase + kc + c0;
    float4 a0 = *(const float4*)Ap;
    float4 a1 = *(const float4*)(Ap + 32 * Fdim);
    float4 b0 = *(const float4*)Wp;
    float4 b1 = *(const float4*)(Wp + 32 * Fdim);
    __syncthreads();
    Ash[c0+0][r0] = a0.x; Ash[c0+1][r0] = a0.y; Ash[c0+2][r0] = a0.z; Ash[c0+3][r0] = a0.w;
    Ash[c0+0][r0+32] = a1.x; Ash[c0+1][r0+32] = a1.y; Ash[c0+2][r0+32] = a1.z; Ash[c0+3][r0+32] = a1.w;
    Bsh[c0+0][r0] = b0.x; Bsh[c0+1][r0] = b0.y; Bsh[c0+2][r0] = b0.z; Bsh[c0+3][r0] = b0.w;
    Bsh[c0+0][r0+32] = b1.x; Bsh[c0+1][r0+32] = b1.y; Bsh[c0+2][r0+32] = b1.z; Bsh[c0+3][r0+32] = b1.w;
    __syncthreads();
    #pragma unroll 8
    for (int k = 0; k < 32; ++k) {
      float4 av = *(const float4*)&Ash[k][ty << 2];
      float4 bv = *(const float4*)&Bsh[k][tx << 2];
      acc[0][0] = fmaf(av.x, bv.x, acc[0][0]); acc[0][1] = fmaf(av.x, bv.y, acc[0][1]);
      acc[0][2] = fmaf(av.x, bv.z, acc[0][2]); acc[0][3] = fmaf(av.x, bv.w, acc[0][3]);
      acc[1][0] = fmaf(av.y, bv.x, acc[1][0]); acc[1][1] = fmaf(av.y, bv.y, acc[1][1]);
      acc[1][2] = fmaf(av.y, bv.z, acc[1][2]); acc[1][3] = fmaf(av.y, bv.w, acc[1][3]);
      acc[2][0] = fmaf(av.z, bv.x, acc[2][0]); acc[2][1] = fmaf(av.z, bv.y, acc[2][1]);
      acc[2][2] = fmaf(av.z, bv.z, acc[2][2]); acc[2][3] = fmaf(av.z, bv.w, acc[2][3]);
      acc[3][0] = fmaf(av.w, bv.x, acc[3][0]); acc[3][1] = fmaf(av.w, bv.y, acc[3][1]);
      acc[3][2] = fmaf(av.w, bv.z, acc[3][2]); acc[3][3] = fmaf(av.w, bv.w, acc[3][3]);
    }
  }
  #pragma unroll
  for (int i = 0; i < 4; ++i) {
    float4 o; o.x = acc[i][0]; o.y = acc[i][1]; o.z = acc[i][2]; o.w = acc[i][3];
    *(float4*)(C + (size_t)(m0 + (ty << 2) + i) * Fdim + n0 + (tx << 2)) = o;
  }
}

// ---------------- scores partial GEMM: Sp[kz][b][p][q] over K-half kz of
// h[b*256+m][o] = hp0 + hp1 + bias[o]. grid (4, 4, 8=b*2+kz), 256 threads.
__global__ __launch_bounds__(256) void score_gemm(const float* __restrict__ hp,
                                                  const float* __restrict__ bias,
                                                  float* __restrict__ Sp) {
  const int b = blockIdx.z >> 1, kz = blockIdx.z & 1;
  const int kbase = kz * 256;
  const int m0 = blockIdx.x * 64, n0 = blockIdx.y * 64;
  const float* h0 = hp;
  const float* h1 = hp + HP_STRIDE;
  float* C = Sp + (size_t)kz * SP_STRIDE + (size_t)b * Pn * Pn;
  const size_t rb = (size_t)b * Pn;
  __shared__ float Ash[32][68];
  __shared__ float Bsh[32][68];
  const int t = threadIdx.x, tx = t & 15, ty = t >> 4;
  const int r0 = t >> 3, c0 = (t & 7) << 2;
  float acc[4][4] = {};

  for (int kc = 0; kc < 256; kc += 32) {
    const int ko = kbase + kc + c0;
    float4 bi = *(const float4*)(bias + ko);
    size_t aoff = (rb + m0 + r0) * Fdim + ko;
    size_t boff = (rb + n0 + r0) * Fdim + ko;
    float4 a0l = *(const float4*)(h0 + aoff);
    float4 a0h = *(const float4*)(h1 + aoff);
    float4 a1l = *(const float4*)(h0 + aoff + 32 * Fdim);
    float4 a1h = *(const float4*)(h1 + aoff + 32 * Fdim);
    float4 b0l = *(const float4*)(h0 + boff);
    float4 b0h = *(const float4*)(h1 + boff);
    float4 b1l = *(const float4*)(h0 + boff + 32 * Fdim);
    float4 b1h = *(const float4*)(h1 + boff + 32 * Fdim);
    float4 a0, a1, b0, b1;
    a0.x = a0l.x + a0h.x + bi.x; a0.y = a0l.y + a0h.y + bi.y;
    a0.z = a0l.z + a0h.z + bi.z; a0.w = a0l.w + a0h.w + bi.w;
    a1.x = a1l.x + a1h.x + bi.x; a1.y = a1l.y + a1h.y + bi.y;
    a1.z = a1l.z + a1h.z + bi.z; a1.w = a1l.w + a1h.w + bi.w;
    b0.x = b0l.x + b0h.x + bi.x; b0.y = b0l.y + b0h.y + bi.y;
    b0.z = b0l.z + b0h.z + bi.z; b0.w = b0l.w + b0h.w + bi.w;
    b1.x = b1l.x + b1h.x + bi.x; b1.y = b1l.y + b1h.y + bi.y;
    b1.z = b1l.z + b1h.z + bi.z; b1.w = b1l.w + b1h.w + bi.w;
    __syncthreads();
    Ash[c0+0][r0] = a0.x; Ash[c0+1][r0] = a0.y; Ash[c0+2][r0] = a0.z; Ash[c0+3][r0] = a0.w;
    Ash[c0+0][r0+32] = a1.x; Ash[c0+1][r0+32] = a1.y; Ash[c0+2][r0+32] = a1.z; Ash[c0+3][r0+32] = a1.w;
    Bsh[c0+0][r0] = b0.x; Bsh[c0+1][r0] = b0.y; Bsh[c0+2][r0] = b0.z; Bsh[c0+3][r0] = b0.w;
    Bsh[c0+0][r0+32] = b1.x; Bsh[c0+1][r0+32] = b1.y; Bsh[c0+2][r0+32] = b1.z; Bsh[c0+3][r0+32] = b1.w;
    __syncthreads();
    #pragma unroll 8
    for (int k = 0; k < 32; ++k) {
      float4 av = *(const float4*)&Ash[k][ty << 2];
      float4 bv = *(const float4*)&Bsh[k][tx << 2];
      acc[0][0] = fmaf(av.x, bv.x, acc[0][0]); acc[0][1] = fmaf(av.x, bv.y, acc[0][1]);
      acc[0][2] = fmaf(av.x, bv.z, acc[0][2]); acc[0][3] = fmaf(av.x, bv.w, acc[0][3]);
      acc[1][0] = fmaf(av.y, bv.x, acc[1][0]); acc[1][1] = fmaf(av.y, bv.y, acc[1][1]);
      acc[1][2] = fmaf(av.y, bv.z, acc[1][2]); acc[1][3] = fmaf(av.y, bv.w, acc[1][3]);
      acc[2][0] = fmaf(av.z, bv.x, acc[2][0]); acc[2][1] = fmaf(av.z, bv.y, acc[2][1]);
      acc[2][2] = fmaf(av.z, bv.z, acc[2][2]); acc[2][3] = fmaf(av.z, bv.w, acc[2][3]);
      acc[3][0] = fmaf(av.w, bv.x, acc[3][0]); acc[3][1] = fmaf(av.w, bv.y, acc[3][1]);
      acc[3][2] = fmaf(av.w, bv.z, acc[3][2]); acc[3][3] = fmaf(av.w, bv.w, acc[3][3]);
    }
  }
  #pragma unroll
  for (int i = 0; i < 4; ++i) {
    float4 o; o.x = acc[i][0]; o.y = acc[i][1]; o.z = acc[i][2]; o.w = acc[i][3];
    *(float4*)(C + (size_t)(m0 + (ty << 2) + i) * Pn + n0 + (tx << 2)) = o;
  }
}

// ---------------- per-row 128-bit label signatures (equal rows => equal sigs)
__device__ __forceinline__ unsigned long long mix64(unsigned long long z) {
  z ^= z >> 33; z *= 0xff51afd7ed558ccdULL;
  z ^= z >> 33; z *= 0xc4ceb9fe1a85ec53ULL;
  z ^= z >> 33; return z;
}
__global__ __launch_bounds__(64) void sig_kernel(const float* __restrict__ labels,
                                                 ulonglong2* __restrict__ sig) {
  const int row = blockIdx.x, t = threadIdx.x;
  const uint4* l4 = (const uint4*)(labels + (size_t)row * Fdim);
  unsigned long long h1 = 0, h2 = 0;
  #pragma unroll
  for (int c = t; c < Fdim / 4; c += 64) {
    uint4 w = l4[c];
    unsigned long long w01 = ((unsigned long long)w.y << 32) | w.x;
    unsigned long long w23 = ((unsigned long long)w.w << 32) | w.z;
    unsigned long long idx = (unsigned long long)c;
    h1 ^= mix64(w01 + idx * 0x9E3779B97F4A7C15ULL + 0x0123456789ABCDEFULL);
    h1 ^= mix64(w23 + idx * 0xC2B2AE3D27D4EB4FULL + 1ULL);
    h2 ^= mix64(w01 ^ (idx * 0x165667B19E3779F9ULL + 7ULL));
    h2 ^= mix64(w23 ^ (idx * 0x27D4EB2F165667C5ULL + 13ULL));
  }
  #pragma unroll
  for (int o = 32; o > 0; o >>= 1) {
    h1 ^= __shfl_down(h1, o, 64);
    h2 ^= __shfl_down(h2, o, 64);
  }
  if (t == 0) { sig[row].x = h1; sig[row].y = h2; }
}

// ---------------- loss: block per (b,p); thread q. Norms from score diagonal.
__global__ __launch_bounds__(256) void loss_kernel(const float* __restrict__ Sp,
                                                   const ulonglong2* __restrict__ sig,
                                                   const float* __restrict__ labels,
                                                   float* __restrict__ acc) {
  const int bp = blockIdx.x, b = bp >> 8, p = bp & 255, q = threadIdx.x;
  __shared__ float sm[4];
  const float* S0 = Sp + (size_t)b * Pn * Pn;
  const float* S1 = S0 + SP_STRIDE;
  const int rowoff = p << 8;
  float Spq = S0[rowoff + q] + S1[rowoff + q];
  float Spp = S0[rowoff + p] + S1[rowoff + p];      // uniform
  float Sqq = S0[(q << 8) + q] + S1[(q << 8) + q];
  float np = fmaxf(sqrtf(Spp), 1e-12f);
  float nq = fmaxf(sqrtf(Sqq), 1e-12f);
  float s = Spq / (np * nq) * INV_TAU;

  // row max
  float m = wave_max(s);
  if ((q & 63) == 0) sm[q >> 6] = m;
  __syncthreads();
  m = fmaxf(fmaxf(sm[0], sm[1]), fmaxf(sm[2], sm[3]));
  __syncthreads();
  float e = expf(s - m);
  float z = wave_sum(e);
  if ((q & 63) == 0) sm[q >> 6] = z;
  __syncthreads();
  z = sm[0] + sm[1] + sm[2] + sm[3];
  __syncthreads();

  float prob = fminf(fmaxf(e / z, EPSC), 1.0f - EPSC);
  float logp = logf(prob);

  // equality: exact row equality <=> d_L1 == 0. sig mismatch => unequal;
  // sig match with q!=p => exact verify (cold path, never taken for random data).
  ulonglong2 sp = sig[(b << 8) + p];
  ulonglong2 sq = sig[(b << 8) + q];
  bool eq;
  if (q == p) {
    eq = true;
  } else if (sp.x == sq.x && sp.y == sq.y) {
    bool v = true;
    const float* lp = labels + (size_t)((b << 8) + p) * Fdim;
    const float* lq = labels + (size_t)((b << 8) + q) * Fdim;
    for (int i = 0; i < Fdim; ++i) v = v && (lp[i] == lq[i]);
    eq = v;
  } else {
    eq = false;
  }

  float cnt = wave_sum(eq ? 1.0f : 0.0f);
  if ((q & 63) == 0) sm[q >> 6] = cnt;
  __syncthreads();
  float n = sm[0] + sm[1] + sm[2] + sm[3];
  __syncthreads();

  float contrib = eq ? (-logf(n) - logp) / n : 0.0f;
  contrib = wave_sum(contrib);
  if ((q & 63) == 0) sm[q >> 6] = contrib;
  __syncthreads();
  if (q == 0) atomicAdd(acc, sm[0] + sm[1] + sm[2] + sm[3]);
}

__global__ void finalize_kernel(const float* __restrict__ acc, float* __restrict__ out) {
  out[0] = acc[0] * (1.0f / (float)(Bz * Pn));
}

extern "C" void kernel_launch(void* const* d_in, const int* in_sizes, int n_in,
                              void* d_out, int out_size, void* d_ws, size_t ws_size,
                              hipStream_t stream) {
  const float* inputs = (const float*)d_in[0];
  const float* labels = (const float*)d_in[1];
  const float* W      = (const float*)d_in[2];
  const float* bias   = (const float*)d_in[3];
  float* out = (float*)d_out;

  char* ws = (char*)d_ws;
  float* acc = (float*)ws;                                   // 4 B
  float* hp  = (float*)(ws + 256);                           // 2 * 2 MB
  float* Sp  = (float*)(ws + 256 + 2 * HP_STRIDE * 4);       // 2 * 1 MB
  ulonglong2* sig = (ulonglong2*)(ws + 256 + 2 * HP_STRIDE * 4 + 2 * SP_STRIDE * 4);  // 16 KB

  hipMemsetAsync(acc, 0, sizeof(float), stream);
  fc_gemm<<<dim3(16, 8, 2), 256, 0, stream>>>(inputs, W, hp);
  sig_kernel<<<Mrows, 64, 0, stream>>>(labels, sig);
  score_gemm<<<dim3(4, 4, 8), 256, 0, stream>>>(hp, bias, Sp);
  loss_kernel<<<Mrows, 256, 0, stream>>>(Sp, sig, labels, acc);
  finalize_kernel<<<1, 1, 0, stream>>>(acc, out);
}

// Round 3
// 100.502 us; speedup vs baseline: 2.6667x; 1.1983x over previous
//
#include <hip/hip_runtime.h>

// MaskPatchClassificationHead — B=4, P=256, F=512
// loss = KL(dist || softmax(x x^T / tau)) batchmean, x = normalize(inputs@W^T + b)
// 3-node graph: fc_sig (fc GEMM K-split2 + label sigs + acc zero)
//            -> score_gemm (h h^T K-split4, h recombined from fc partials + bias)
//            -> loss (diag norms once/block, 4 rows/block, done-counter finalize)

#define INV_TAU (1.0f / 0.07f)
#define EPSC 1e-5f

constexpr int Bz = 4;
constexpr int Pn = 256;
constexpr int Fdim = 512;
constexpr int Mrows = Bz * Pn;                       // 1024
constexpr size_t HP_STRIDE = (size_t)Mrows * Fdim;   // per fc K-half partial
constexpr size_t SP_STRIDE = (size_t)Bz * Pn * Pn;   // per score K-quarter partial

__device__ __forceinline__ float wave_sum(float v) {
  #pragma unroll
  for (int o = 32; o > 0; o >>= 1) v += __shfl_down(v, o, 64);
  return v;
}
__device__ __forceinline__ float wave_max(float v) {
  #pragma unroll
  for (int o = 32; o > 0; o >>= 1) v = fmaxf(v, __shfl_down(v, o, 64));
  return v;
}
__device__ __forceinline__ unsigned long long mix64(unsigned long long z) {
  z ^= z >> 33; z *= 0xff51afd7ed558ccdULL;
  z ^= z >> 33; z *= 0xc4ceb9fe1a85ec53ULL;
  z ^= z >> 33; return z;
}

// ---------------- fc partial GEMM + label sigs + accumulator zeroing
// hp[z][m][n] = sum_{k in half z} A[m][k] W[n][k]
// 64x64 tile, 2x4 micro, BK=32, 512 threads. grid (16, 8, 2) = 256 blocks (1/CU).
__global__ __launch_bounds__(512) void fc_sig(const float* __restrict__ A,
                                              const float* __restrict__ W,
                                              const float* __restrict__ labels,
                                              float* __restrict__ hp,
                                              ulonglong2* __restrict__ sig,
                                              float* __restrict__ acc,
                                              unsigned int* __restrict__ done) {
  const int t = threadIdx.x;
  const int bid = blockIdx.x + 16 * (blockIdx.y + 8 * blockIdx.z);
  if (bid == 0 && t == 0) { acc[0] = 0.0f; done[0] = 0u; }

  // --- label signatures: 4 rows per block, one 64-lane group per row
  {
    const int g = t >> 6, lane = t & 63;
    if (g < 4) {
      const int row = bid * 4 + g;
      const uint4* l4 = (const uint4*)(labels + (size_t)row * Fdim);
      unsigned long long h1 = 0, h2 = 0;
      #pragma unroll
      for (int c = lane; c < Fdim / 4; c += 64) {
        uint4 w = l4[c];
        unsigned long long w01 = ((unsigned long long)w.y << 32) | w.x;
        unsigned long long w23 = ((unsigned long long)w.w << 32) | w.z;
        unsigned long long idx = (unsigned long long)c;
        h1 ^= mix64(w01 + idx * 0x9E3779B97F4A7C15ULL + 0x0123456789ABCDEFULL);
        h1 ^= mix64(w23 + idx * 0xC2B2AE3D27D4EB4FULL + 1ULL);
        h2 ^= mix64(w01 ^ (idx * 0x165667B19E3779F9ULL + 7ULL));
        h2 ^= mix64(w23 ^ (idx * 0x27D4EB2F165667C5ULL + 13ULL));
      }
      #pragma unroll
      for (int o = 32; o > 0; o >>= 1) {
        h1 ^= __shfl_down(h1, o, 64);
        h2 ^= __shfl_down(h2, o, 64);
      }
      if (lane == 0) { sig[row].x = h1; sig[row].y = h2; }
    }
  }

  // --- fc GEMM
  const int m0 = blockIdx.x * 64, n0 = blockIdx.y * 64;
  const int kbase = blockIdx.z * 256;
  float* C = hp + (size_t)blockIdx.z * HP_STRIDE;
  __shared__ float Ash[32][68];  // [k][m]
  __shared__ float Bsh[32][68];  // [k][n]
  const int tx = t & 15, ty = t >> 4;            // ty 0..31 -> rows ty*2+{0,1}
  const int r0 = t >> 3, c0 = (t & 7) << 2;      // staging: row r0, k-cols c0..c0+3
  float acc2[2][4] = {};

  for (int kc = 0; kc < 256; kc += 32) {
    const float* Ap = A + (size_t)(m0 + r0) * Fdim + kbase + kc + c0;
    const float* Wp = W + (size_t)(n0 + r0) * Fdim + kbase + kc + c0;
    float4 a = *(const float4*)Ap;
    float4 b = *(const float4*)Wp;
    __syncthreads();
    Ash[c0+0][r0] = a.x; Ash[c0+1][r0] = a.y; Ash[c0+2][r0] = a.z; Ash[c0+3][r0] = a.w;
    Bsh[c0+0][r0] = b.x; Bsh[c0+1][r0] = b.y; Bsh[c0+2][r0] = b.z; Bsh[c0+3][r0] = b.w;
    __syncthreads();
    #pragma unroll 8
    for (int k = 0; k < 32; ++k) {
      float2 av = *(const float2*)&Ash[k][ty << 1];
      float4 bv = *(const float4*)&Bsh[k][tx << 2];
      acc2[0][0] = fmaf(av.x, bv.x, acc2[0][0]); acc2[0][1] = fmaf(av.x, bv.y, acc2[0][1]);
      acc2[0][2] = fmaf(av.x, bv.z, acc2[0][2]); acc2[0][3] = fmaf(av.x, bv.w, acc2[0][3]);
      acc2[1][0] = fmaf(av.y, bv.x, acc2[1][0]); acc2[1][1] = fmaf(av.y, bv.y, acc2[1][1]);
      acc2[1][2] = fmaf(av.y, bv.z, acc2[1][2]); acc2[1][3] = fmaf(av.y, bv.w, acc2[1][3]);
    }
  }
  #pragma unroll
  for (int i = 0; i < 2; ++i) {
    float4 o; o.x = acc2[i][0]; o.y = acc2[i][1]; o.z = acc2[i][2]; o.w = acc2[i][3];
    *(float4*)(C + (size_t)(m0 + (ty << 1) + i) * Fdim + n0 + (tx << 2)) = o;
  }
}

// ---------------- scores partial GEMM: Sp[kz][b][p][q], K-quarter kz of
// h[b*256+m][o] = hp0 + hp1 + bias[o]. 64x64 tile, 2x4 micro, 512 threads.
// grid (4, 4, 16 = b*4+kz) = 256 blocks (1/CU).
__global__ __launch_bounds__(512) void score_gemm(const float* __restrict__ hp,
                                                  const float* __restrict__ bias,
                                                  float* __restrict__ Sp) {
  const int b = blockIdx.z >> 2, kz = blockIdx.z & 3;
  const int kbase = kz * 128;
  const int m0 = blockIdx.x * 64, n0 = blockIdx.y * 64;
  const float* h0 = hp;
  const float* h1 = hp + HP_STRIDE;
  float* C = Sp + (size_t)kz * SP_STRIDE + (size_t)b * Pn * Pn;
  const size_t rb = (size_t)b * Pn;
  __shared__ float Ash[32][68];
  __shared__ float Bsh[32][68];
  const int t = threadIdx.x, tx = t & 15, ty = t >> 4;
  const int r0 = t >> 3, c0 = (t & 7) << 2;
  float acc2[2][4] = {};

  for (int kc = 0; kc < 128; kc += 32) {
    const int ko = kbase + kc + c0;
    float4 bi = *(const float4*)(bias + ko);
    size_t aoff = (rb + m0 + r0) * Fdim + ko;
    size_t boff = (rb + n0 + r0) * Fdim + ko;
    float4 al = *(const float4*)(h0 + aoff);
    float4 ah = *(const float4*)(h1 + aoff);
    float4 bl = *(const float4*)(h0 + boff);
    float4 bh = *(const float4*)(h1 + boff);
    float4 a, b;
    a.x = al.x + ah.x + bi.x; a.y = al.y + ah.y + bi.y;
    a.z = al.z + ah.z + bi.z; a.w = al.w + ah.w + bi.w;
    b.x = bl.x + bh.x + bi.x; b.y = bl.y + bh.y + bi.y;
    b.z = bl.z + bh.z + bi.z; b.w = bl.w + bh.w + bi.w;
    __syncthreads();
    Ash[c0+0][r0] = a.x; Ash[c0+1][r0] = a.y; Ash[c0+2][r0] = a.z; Ash[c0+3][r0] = a.w;
    Bsh[c0+0][r0] = b.x; Bsh[c0+1][r0] = b.y; Bsh[c0+2][r0] = b.z; Bsh[c0+3][r0] = b.w;
    __syncthreads();
    #pragma unroll 8
    for (int k = 0; k < 32; ++k) {
      float2 av = *(const float2*)&Ash[k][ty << 1];
      float4 bv = *(const float4*)&Bsh[k][tx << 2];
      acc2[0][0] = fmaf(av.x, bv.x, acc2[0][0]); acc2[0][1] = fmaf(av.x, bv.y, acc2[0][1]);
      acc2[0][2] = fmaf(av.x, bv.z, acc2[0][2]); acc2[0][3] = fmaf(av.x, bv.w, acc2[0][3]);
      acc2[1][0] = fmaf(av.y, bv.x, acc2[1][0]); acc2[1][1] = fmaf(av.y, bv.y, acc2[1][1]);
      acc2[1][2] = fmaf(av.y, bv.z, acc2[1][2]); acc2[1][3] = fmaf(av.y, bv.w, acc2[1][3]);
    }
  }
  #pragma unroll
  for (int i = 0; i < 2; ++i) {
    float4 o; o.x = acc2[i][0]; o.y = acc2[i][1]; o.z = acc2[i][2]; o.w = acc2[i][3];
    *(float4*)(C + (size_t)(m0 + (ty << 1) + i) * Pn + n0 + (tx << 2)) = o;
  }
}

// ---------------- loss: 256 blocks x 256 thr; block = (batch b, 4 rows).
// Diagonal inv-norms once per block into LDS; per-lane contribs accumulated
// across rows; one atomicAdd per block; last block finalizes out.
__global__ __launch_bounds__(256) void loss_kernel(const float* __restrict__ Sp,
                                                   const ulonglong2* __restrict__ sig,
                                                   const float* __restrict__ labels,
                                                   float* __restrict__ acc,
                                                   unsigned int* __restrict__ done,
                                                   float* __restrict__ out) {
  const int bx = blockIdx.x;
  const int b = bx >> 6, p0 = (bx & 63) * 4;
  const int q = threadIdx.x;
  __shared__ float invn[256];
  __shared__ float red[12];
  const float* S0 = Sp + (size_t)b * Pn * Pn;
  const float* S1 = S0 + SP_STRIDE;
  const float* S2 = S0 + 2 * SP_STRIDE;
  const float* S3 = S0 + 3 * SP_STRIDE;

  // diagonal norms (once per block)
  {
    const int d = q * 257;  // q*256 + q
    float Sqq = S0[d] + S1[d] + S2[d] + S3[d];
    invn[q] = 1.0f / fmaxf(sqrtf(Sqq), 1e-12f);
  }
  const ulonglong2 sq = sig[(b << 8) + q];
  __syncthreads();

  const int w = q >> 6;
  float lane_contrib = 0.0f;

  #pragma unroll
  for (int i = 0; i < 4; ++i) {
    const int p = p0 + i;
    const int ro = p << 8;
    float Spq = S0[ro + q] + S1[ro + q] + S2[ro + q] + S3[ro + q];
    float s = Spq * invn[p] * invn[q] * INV_TAU;

    // equality: exact row equality <=> L1 dist == 0. sig mismatch => unequal;
    // sig match with q!=p => exact verify (cold path).
    ulonglong2 sp = sig[(b << 8) + p];
    bool eq;
    if (q == p) eq = true;
    else if (sp.x == sq.x && sp.y == sq.y) {
      bool v = true;
      const float* lp = labels + (size_t)((b << 8) + p) * Fdim;
      const float* lq = labels + (size_t)((b << 8) + q) * Fdim;
      for (int j = 0; j < Fdim; ++j) v = v && (lp[j] == lq[j]);
      eq = v;
    } else eq = false;

    // row max
    float m = wave_max(s);
    if ((q & 63) == 0) red[w] = m;
    __syncthreads();
    m = fmaxf(fmaxf(red[0], red[1]), fmaxf(red[2], red[3]));

    float e = expf(s - m);
    float zc = wave_sum(e);
    float cc = wave_sum(eq ? 1.0f : 0.0f);
    if ((q & 63) == 0) { red[4 + w] = zc; red[8 + w] = cc; }
    __syncthreads();
    float z = red[4] + red[5] + red[6] + red[7];
    float n = red[8] + red[9] + red[10] + red[11];

    float prob = fminf(fmaxf(e / z, EPSC), 1.0f - EPSC);
    if (eq) lane_contrib += (-logf(n) - logf(prob)) / n;
    __syncthreads();  // red reuse next iter
  }

  // block reduce + accumulate
  float c = wave_sum(lane_contrib);
  if ((q & 63) == 0) red[w] = c;
  __syncthreads();
  if (q == 0) {
    atomicAdd(acc, red[0] + red[1] + red[2] + red[3]);
    __threadfence();
    unsigned int v = atomicAdd(done, 1u);
    if (v == 255u) {  // last of 256 blocks: all acc adds visible
      float tot = atomicAdd(acc, 0.0f);
      out[0] = tot * (1.0f / (float)(Bz * Pn));
    }
  }
}

extern "C" void kernel_launch(void* const* d_in, const int* in_sizes, int n_in,
                              void* d_out, int out_size, void* d_ws, size_t ws_size,
                              hipStream_t stream) {
  const float* inputs = (const float*)d_in[0];
  const float* labels = (const float*)d_in[1];
  const float* W      = (const float*)d_in[2];
  const float* bias   = (const float*)d_in[3];
  float* out = (float*)d_out;

  char* ws = (char*)d_ws;
  float* acc         = (float*)ws;                    // 4 B
  unsigned int* done = (unsigned int*)(ws + 4);       // 4 B
  float* hp = (float*)(ws + 256);                     // 2 * 2 MB fc partials
  float* Sp = (float*)(ws + 256 + 2 * HP_STRIDE * 4); // 4 * 1 MB score partials
  ulonglong2* sig = (ulonglong2*)(ws + 256 + 2 * HP_STRIDE * 4 + 4 * SP_STRIDE * 4);

  fc_sig<<<dim3(16, 8, 2), 512, 0, stream>>>(inputs, W, labels, hp, sig, acc, done);
  score_gemm<<<dim3(4, 4, 16), 512, 0, stream>>>(hp, bias, Sp);
  loss_kernel<<<256, 256, 0, stream>>>(Sp, sig, labels, acc, done, out);
}